// Round 10
// baseline (106.805 us; speedup 1.0000x reference)
//
#include <hip/hip_runtime.h>

// AGDN graph layer, fused. B=8, L=256, H=128, E=32.
//  - edge_h never materialized: Wea = We2@Wa_edge, Wem = We2@Wm_edge precomputed.
//  - Wm2 hoisted out of the pair loop (softmax weights sum to 1).
//  - j-compaction: only valid j's processed (order-preserving per-batch slices).
//  - permuted cols (frag n <-> col 64*(n>>2)+4*l15+(n&3)) -> all per-lane
//    parameter/epilogue accesses are contiguous f32x4 / ushort4.
//  - R9/R10: WAVE-INDEPENDENT kernC. Each wave owns 16 j x full 128 h: T
//    transpose in per-wave 4KB LDS (in-wave DS ordering, NO barrier), per-wave
//    16-j softmax partial in registers, ONE final barrier for the 4-wave
//    log-sum-exp merge.
//  - R10 FIX: R9's s16 had a spurious *0.0625 — the shfl_xor(16/32) butterfly
//    reduces over the 4 l4-groups ONLY (16 j's, no l15 duplication), so the
//    softmax denominator was 16x under-counted -> absmax 4.48. s16 = sl.

typedef __attribute__((ext_vector_type(8))) short bhalf8;
typedef __attribute__((ext_vector_type(4))) float f32x4;

__device__ __forceinline__ short f2bf(float f) {
  union { float f; unsigned u; } v; v.f = f;
  unsigned r = (v.u + 0x7FFFu + ((v.u >> 16) & 1u)) >> 16;  // RNE
  return (short)r;
}
__device__ __forceinline__ unsigned cvt_pk(float lo, float hi) {
  unsigned r;
  asm("v_cvt_pk_bf16_f32 %0, %1, %2" : "=v"(r) : "v"(lo), "v"(hi));
  return r;
}
__device__ __forceinline__ float rawexp2(float x) {
  float r;
  asm("v_exp_f32 %0, %1" : "=v"(r) : "v"(x));
  return r;
}
__device__ __forceinline__ float rawrcp(float x) {
  float r;
  asm("v_rcp_f32 %0, %1" : "=v"(r) : "v"(x));
  return r;
}
__device__ __forceinline__ float bf2f(unsigned short x) {
  union { unsigned u; float f; } t; t.u = ((unsigned)x) << 16; return t.f;
}
__device__ __forceinline__ f32x4 mfma16(bhalf8 a, bhalf8 b, f32x4 c) {
  return __builtin_amdgcn_mfma_f32_16x16x32_bf16(a, b, c, 0, 0, 0);
}

// ---------------------------------------------------------------------------
// Fused pre-kernel (unchanged): weight packing / compaction / node GEMVs.
// ---------------------------------------------------------------------------
__global__ __launch_bounds__(256) void fusedPre(
    const float* __restrict__ hsrc, const int* __restrict__ vmask,
    const float* __restrict__ We1, const float* __restrict__ We2,
    const float* __restrict__ be2, const float* __restrict__ Wa1,
    const float* __restrict__ ba1, const float* __restrict__ Wm1,
    const float* __restrict__ bm1,
    short* __restrict__ we1p, short* __restrict__ weap, short* __restrict__ wemp,
    float* __restrict__ bea, float* __restrict__ bem,
    int* __restrict__ compact, int* __restrict__ bstart, int* __restrict__ cnt,
    float* __restrict__ asrcb, unsigned short* __restrict__ adst_bf,
    float* __restrict__ hmb) {
  __shared__ float shf[8][128];
  __shared__ int wsum[4];
  const int blk = blockIdx.x;
  const int tid = threadIdx.x;

  if (blk < 145) {
    int u = blk * 256 + tid;
    if (u < 4096) {                       // We1 packed, PERMUTED h_mid cols
      int e = u & 7, lane = (u >> 3) & 63, nt = u >> 9;
      int k = 8 * (lane >> 4) + e;
      int n = 64 * (nt >> 2) + 4 * (lane & 15) + (nt & 3);
      we1p[u] = f2bf(We1[k * 128 + n]);
    } else if (u < 20480) {               // Wea packed, permuted h_out cols
      int v = u - 4096;
      int e = v & 7, lane = (v >> 3) & 63, nt = (v >> 9) & 7, ks = v >> 12;
      int k = 32 * ks + 8 * (lane >> 4) + e;
      int co = 64 * (nt >> 2) + 4 * (lane & 15) + (nt & 3);
      float a0 = 0.f, a1 = 0.f, a2 = 0.f, a3 = 0.f;
      for (int c = 0; c < 128; c += 4) {
        const float4 w4 = *(const float4*)&We2[k * 128 + c];
        a0 = fmaf(w4.x, Wa1[(256 + c + 0) * 128 + co], a0);
        a1 = fmaf(w4.y, Wa1[(256 + c + 1) * 128 + co], a1);
        a2 = fmaf(w4.z, Wa1[(256 + c + 2) * 128 + co], a2);
        a3 = fmaf(w4.w, Wa1[(256 + c + 3) * 128 + co], a3);
      }
      weap[v] = f2bf((a0 + a1) + (a2 + a3));
    } else if (u < 36864) {               // Wem packed, permuted h_out cols
      int v = u - 20480;
      int e = v & 7, lane = (v >> 3) & 63, nt = (v >> 9) & 7, ks = v >> 12;
      int k = 32 * ks + 8 * (lane >> 4) + e;
      int co = 64 * (nt >> 2) + 4 * (lane & 15) + (nt & 3);
      float a0 = 0.f, a1 = 0.f, a2 = 0.f, a3 = 0.f;
      for (int c = 0; c < 128; c += 4) {
        const float4 w4 = *(const float4*)&We2[k * 128 + c];
        a0 = fmaf(w4.x, Wm1[(128 + c + 0) * 128 + co], a0);
        a1 = fmaf(w4.y, Wm1[(128 + c + 1) * 128 + co], a1);
        a2 = fmaf(w4.z, Wm1[(128 + c + 2) * 128 + co], a2);
        a3 = fmaf(w4.w, Wm1[(128 + c + 3) * 128 + co], a3);
      }
      wemp[v] = f2bf((a0 + a1) + (a2 + a3));
    } else if (u < 36992) {
      int hc = u - 36864;
      float acc = ba1[hc];
      for (int c = 0; c < 128; ++c)
        acc = fmaf(be2[c], Wa1[(256 + c) * 128 + hc], acc);
      bea[hc] = acc;
    } else if (u < 37120) {
      int hc = u - 36992;
      float acc = bm1[hc];
      for (int c = 0; c < 128; ++c)
        acc = fmaf(be2[c], Wm1[(128 + c) * 128 + hc], acc);
      bem[hc] = acc;
    }
  } else if (blk == 145) {  // compaction
    int loc[8], c = 0;
#pragma unroll
    for (int q = 0; q < 8; ++q) {
      int v = vmask[tid * 8 + q] != 0;
      loc[q] = v;
      c += v;
    }
    const int l = tid & 63, w = tid >> 6;
    int pre = c;
#pragma unroll
    for (int o = 1; o < 64; o <<= 1) {
      int t = __shfl_up(pre, o);
      if (l >= o) pre += t;
    }
    if (l == 63) wsum[w] = pre;
    __syncthreads();
    int base = 0;
    for (int q = 0; q < w; ++q) base += wsum[q];
    int off = base + pre - c;
    if ((tid & 31) == 0) bstart[tid >> 5] = off;
#pragma unroll
    for (int q = 0; q < 8; ++q)
      if (loc[q]) compact[off++] = tid * 8 + q;
    if (tid == 255) { cnt[0] = off; bstart[8] = off; }
  } else {  // node GEMVs
    const int base = (blk - 146) * 8;
    const int col = tid & 127, half = tid >> 7;
#pragma unroll
    for (int g = 0; g < 4; ++g)
      shf[half * 4 + g][col] = hsrc[(size_t)(base + half * 4 + g) * 128 + col];
    __syncthreads();
    float aS[4], aD[4], aM[4];
#pragma unroll
    for (int g = 0; g < 4; ++g) { aS[g] = 0.f; aD[g] = 0.f; aM[g] = 0.f; }
    for (int k = 0; k < 128; k += 4) {
      float s0 = Wa1[(k + 0) * 128 + col], s1 = Wa1[(k + 1) * 128 + col];
      float s2 = Wa1[(k + 2) * 128 + col], s3 = Wa1[(k + 3) * 128 + col];
      float d0 = Wa1[(128 + k + 0) * 128 + col], d1 = Wa1[(128 + k + 1) * 128 + col];
      float d2 = Wa1[(128 + k + 2) * 128 + col], d3 = Wa1[(128 + k + 3) * 128 + col];
      float m0 = Wm1[(k + 0) * 128 + col], m1 = Wm1[(k + 1) * 128 + col];
      float m2 = Wm1[(k + 2) * 128 + col], m3 = Wm1[(k + 3) * 128 + col];
#pragma unroll
      for (int g = 0; g < 4; ++g) {
        const float4 hv = *(const float4*)&shf[half * 4 + g][k];
        aS[g] = fmaf(hv.x, s0, fmaf(hv.y, s1, fmaf(hv.z, s2, fmaf(hv.w, s3, aS[g]))));
        aD[g] = fmaf(hv.x, d0, fmaf(hv.y, d1, fmaf(hv.z, d2, fmaf(hv.w, d3, aD[g]))));
        aM[g] = fmaf(hv.x, m0, fmaf(hv.y, m1, fmaf(hv.z, m2, fmaf(hv.w, m3, aM[g]))));
      }
    }
#pragma unroll
    for (int g = 0; g < 4; ++g) {
      size_t o = (size_t)(base + half * 4 + g) * 128 + col;
      asrcb[o] = aS[g];
      adst_bf[o] = (unsigned short)f2bf(aD[g]);
      hmb[o] = aM[g];
    }
  }
}

// ---------------------------------------------------------------------------
// Kernel C: one block per (valid node rank v, chunk q of 64 VALID j's).
// 4 INDEPENDENT waves; wave w owns j-group [16w,16w+16) x full 128 h.
// Per-wave LDS T-transpose (4KB, in-wave ordering, no barrier). One final
// barrier for the 4-wave log-sum-exp merge.
// ---------------------------------------------------------------------------
__global__ __launch_bounds__(256) void kernC(
    const float* __restrict__ ef, const int* __restrict__ compact,
    const int* __restrict__ bstart, const int* __restrict__ cnt,
    const short* __restrict__ we1p, const short* __restrict__ weap,
    const short* __restrict__ wemp, const float* __restrict__ asrcb,
    const unsigned short* __restrict__ adst_bf, const float* __restrict__ hmb,
    const float* __restrict__ wa2, const float* __restrict__ be1,
    const float* __restrict__ ba2, const float* __restrict__ bea,
    const float* __restrict__ bem, float* __restrict__ aggp,
    float2* __restrict__ msbuf) {
  const int nv = cnt[0];
  const int v = blockIdx.x >> 2;
  if (v >= nv) return;
  const int q = blockIdx.x & 3;
  const int blk = compact[v];
  const int b = blk >> 8;
  const int jb0 = bstart[b];
  const int nb = bstart[b + 1] - jb0;
  if (q * 64 >= nb) return;
  const int tid = threadIdx.x;
  const int w = tid >> 6, l = tid & 63;
  const int l15 = l & 15, l4 = l >> 4;

  __shared__ short Tl[4][16 * 128];               // 4KB per wave, swizzled
  __shared__ __align__(16) float aggL[4][128];
  __shared__ float2 msL[4];

  // ---- EF load for this wave's 16 rows (earliest possible issue) ----
  {
    int idxT = q * 64 + 16 * w + l15;
    int jrT = compact[jb0 + (idxT < nb ? idxT : nb - 1)] & 255;
    const float* p = ef + (((size_t)blk * 256 + jrT) * 32 + 8 * l4);
    float4 f0 = *(const float4*)p;
    float4 f1 = *(const float4*)(p + 4);

    // per-lane parameter slices (permuted col(n) = 64*(n>>2)+4*l15+(n&3))
    const f32x4 b40 = *(const f32x4*)&be1[4 * l15];
    const f32x4 b41 = *(const f32x4*)&be1[64 + 4 * l15];

    // ---- T = relu(EF @ We1perm + be1perm) -> Tl[w] (natural h_mid order) ----
    f32x4 acc[8];
#pragma unroll
    for (int n = 0; n < 8; ++n) acc[n] = {0.f, 0.f, 0.f, 0.f};
    union { bhalf8 v8; unsigned u[4]; } a;
    a.u[0] = cvt_pk(f0.x, f0.y);
    a.u[1] = cvt_pk(f0.z, f0.w);
    a.u[2] = cvt_pk(f1.x, f1.y);
    a.u[3] = cvt_pk(f1.z, f1.w);
#pragma unroll
    for (int n = 0; n < 8; ++n) {
      bhalf8 bfr = *(const bhalf8*)(we1p + (size_t)(n * 64 + l) * 8);
      acc[n] = mfma16(a.v8, bfr, acc[n]);
    }
    char* Tb = (char*)Tl[w];
#pragma unroll
    for (int r = 0; r < 4; ++r) {
      int rr = 4 * l4 + r;
      float v0 = fmaxf(acc[0][r] + b40[0], 0.f);
      float v1 = fmaxf(acc[1][r] + b40[1], 0.f);
      float v2 = fmaxf(acc[2][r] + b40[2], 0.f);
      float v3 = fmaxf(acc[3][r] + b40[3], 0.f);
      float v4 = fmaxf(acc[4][r] + b41[0], 0.f);
      float v5 = fmaxf(acc[5][r] + b41[1], 0.f);
      float v6 = fmaxf(acc[6][r] + b41[2], 0.f);
      float v7 = fmaxf(acc[7][r] + b41[3], 0.f);
      uint2 p0, p1;
      p0.x = cvt_pk(v0, v1); p0.y = cvt_pk(v2, v3);
      p1.x = cvt_pk(v4, v5); p1.y = cvt_pk(v6, v7);
      int swz = (rr & 7) << 4;
      *(uint2*)(Tb + ((rr * 256 + 8 * l15) ^ swz)) = p0;
      *(uint2*)(Tb + ((rr * 256 + 128 + 8 * l15) ^ swz)) = p1;
    }
  }
  // no barrier: wave reads its own Tl[w]; same-wave DS ops complete in order

  const float ba2v = ba2[0];
  const float RS = 0.08838834764831845f;          // 1/sqrt(128)
  const char* Tb = (const char*)Tl[w];
  const int swzR = (l15 & 7) << 4;

  const f32x4 asv0 = *(const f32x4*)&asrcb[(size_t)blk * 128 + 4 * l15] +
                     *(const f32x4*)&bea[4 * l15];
  const f32x4 asv1 = *(const f32x4*)&asrcb[(size_t)blk * 128 + 64 + 4 * l15] +
                     *(const f32x4*)&bea[64 + 4 * l15];
  const f32x4 wav0 = *(const f32x4*)&wa2[4 * l15];
  const f32x4 wav1 = *(const f32x4*)&wa2[64 + 4 * l15];
  float wtot = (wav0[0] + wav0[1] + wav0[2] + wav0[3]) +
               (wav1[0] + wav1[1] + wav1[2] + wav1[3]);
  wtot += __shfl_xor(wtot, 1);
  wtot += __shfl_xor(wtot, 2);
  wtot += __shfl_xor(wtot, 4);
  wtot += __shfl_xor(wtot, 8);

  // adst prefetch (per r: 2 x ushort4 via col permutation)
  ushort4 adL[4], adH[4];
#pragma unroll
  for (int r = 0; r < 4; ++r) {
    int idxr = q * 64 + 16 * w + 4 * l4 + r;
    int jg = compact[jb0 + (idxr < nb ? idxr : nb - 1)] & 255;
    const unsigned short* ap = adst_bf + (size_t)(b * 256 + jg) * 128;
    adL[r] = *(const ushort4*)(ap + 4 * l15);
    adH[r] = *(const ushort4*)(ap + 64 + 4 * l15);
  }

  // ---- EA = T @ Wea ; logits ----
  float logit[4];
  {
    f32x4 acc[8];
#pragma unroll
    for (int n = 0; n < 8; ++n) acc[n] = {0.f, 0.f, 0.f, 0.f};
#pragma unroll
    for (int ks = 0; ks < 4; ++ks) {
      bhalf8 af = *(const bhalf8*)(Tb + ((l15 * 256 + ks * 64 + 16 * l4) ^ swzR));
#pragma unroll
      for (int n = 0; n < 8; ++n) {
        bhalf8 bf2 = *(const bhalf8*)(weap + (size_t)((ks * 8 + n) * 64 + l) * 8);
        acc[n] = mfma16(af, bf2, acc[n]);
      }
    }
#pragma unroll
    for (int r = 0; r < 4; ++r) {
      float racc = 0.f;
      float ad[8] = {bf2f(adL[r].x), bf2f(adL[r].y), bf2f(adL[r].z),
                     bf2f(adL[r].w), bf2f(adH[r].x), bf2f(adH[r].y),
                     bf2f(adH[r].z), bf2f(adH[r].w)};
      float as[8] = {asv0[0], asv0[1], asv0[2], asv0[3],
                     asv1[0], asv1[1], asv1[2], asv1[3]};
      float wv[8] = {wav0[0], wav0[1], wav0[2], wav0[3],
                     wav1[0], wav1[1], wav1[2], wav1[3]};
#pragma unroll
      for (int n = 0; n < 8; ++n) {
        float x = acc[n][r] + as[n] + ad[n];
        float e = rawexp2(x * 2.885390082f);
        racc = fmaf(wv[n], rawrcp(e + 1.f), racc);
      }
      racc += __shfl_xor(racc, 1);
      racc += __shfl_xor(racc, 2);
      racc += __shfl_xor(racc, 4);
      racc += __shfl_xor(racc, 8);
      logit[r] = wtot - 2.f * racc;   // uniform across l15 lanes
    }
  }

  // ---- per-wave softmax over its 16 j's (registers only) ----
  float m16, s16, wj[4];
  {
    float sc[4];
#pragma unroll
    for (int r = 0; r < 4; ++r) {
      int idxr = q * 64 + 16 * w + 4 * l4 + r;
      sc[r] = (idxr < nb) ? (logit[r] + ba2v) * RS : -1e30f;
    }
    float mx = fmaxf(fmaxf(sc[0], sc[1]), fmaxf(sc[2], sc[3]));
    mx = fmaxf(mx, __shfl_xor(mx, 16));
    mx = fmaxf(mx, __shfl_xor(mx, 32));
    m16 = mx;
    float sl = 0.f;
#pragma unroll
    for (int r = 0; r < 4; ++r) {
      wj[r] = __expf(sc[r] - m16);
      sl += wj[r];
    }
    sl += __shfl_xor(sl, 16);
    sl += __shfl_xor(sl, 32);
    s16 = sl;   // R10 fix: butterfly covers the 4 l4-groups only (16 j's);
                // values are uniform across l15 lanes, NOT summed over them.
  }

  // ---- EM = T @ Wem ; weighted relu accumulate ----
  float part[8] = {0.f, 0.f, 0.f, 0.f, 0.f, 0.f, 0.f, 0.f};
  {
    const f32x4 hv0 = *(const f32x4*)&hmb[(size_t)blk * 128 + 4 * l15] +
                      *(const f32x4*)&bem[4 * l15];
    const f32x4 hv1 = *(const f32x4*)&hmb[(size_t)blk * 128 + 64 + 4 * l15] +
                      *(const f32x4*)&bem[64 + 4 * l15];
    f32x4 acc[8];
#pragma unroll
    for (int n = 0; n < 8; ++n) acc[n] = {0.f, 0.f, 0.f, 0.f};
#pragma unroll
    for (int ks = 0; ks < 4; ++ks) {
      bhalf8 af = *(const bhalf8*)(Tb + ((l15 * 256 + ks * 64 + 16 * l4) ^ swzR));
#pragma unroll
      for (int n = 0; n < 8; ++n) {
        bhalf8 bf2 = *(const bhalf8*)(wemp + (size_t)((ks * 8 + n) * 64 + l) * 8);
        acc[n] = mfma16(af, bf2, acc[n]);
      }
    }
    float hvv[8] = {hv0[0], hv0[1], hv0[2], hv0[3],
                    hv1[0], hv1[1], hv1[2], hv1[3]};
#pragma unroll
    for (int r = 0; r < 4; ++r)
#pragma unroll
      for (int n = 0; n < 8; ++n) {
        float vv = fmaxf(acc[n][r] + hvv[n], 0.f);
        part[n] = fmaf(wj[r], vv, part[n]);
      }
  }

  // reduce part over the 4 l4-groups (j coverage), write wave result
#pragma unroll
  for (int n = 0; n < 8; ++n) {
    part[n] += __shfl_xor(part[n], 16);
    part[n] += __shfl_xor(part[n], 32);
  }
  if (l4 == 0) {
    f32x4 p0 = {part[0], part[1], part[2], part[3]};
    f32x4 p1 = {part[4], part[5], part[6], part[7]};
    *(f32x4*)&aggL[w][4 * l15] = p0;
    *(f32x4*)&aggL[w][64 + 4 * l15] = p1;
  }
  if (l == 0) msL[w] = make_float2(m16, s16);
  __syncthreads();   // the ONLY block-wide barrier

  // ---- merge 4 waves (log-sum-exp), write chunk partials ----
  if (tid < 128) {
    float2 A0 = msL[0], A1 = msL[1], A2 = msL[2], A3 = msL[3];
    float m = fmaxf(fmaxf(A0.x, A1.x), fmaxf(A2.x, A3.x));
    float e0 = __expf(A0.x - m), e1 = __expf(A1.x - m);
    float e2 = __expf(A2.x - m), e3 = __expf(A3.x - m);
    float agg = e0 * aggL[0][tid] + e1 * aggL[1][tid] + e2 * aggL[2][tid] +
                e3 * aggL[3][tid];
    aggp[((size_t)blk * 4 + q) * 128 + tid] = agg;
    if (tid == 0) {
      float s = e0 * A0.y + e1 * A1.y + e2 * A2.y + e3 * A3.y;
      msbuf[blk * 4 + q] = make_float2(m, s);
    }
  }
}

// ---------------------------------------------------------------------------
// Kernel D (unchanged from R8): merge nq chunks; MLP; residual; LN; mask.
// ---------------------------------------------------------------------------
__global__ __launch_bounds__(1024) void kernD(
    const float* __restrict__ hsrc, const int* __restrict__ vmask,
    const int* __restrict__ bstart, const float* __restrict__ aggp,
    const float2* __restrict__ msbuf, const float* __restrict__ Wm2,
    const float* __restrict__ bm2, const float* __restrict__ Wo1,
    const float* __restrict__ bo1, const float* __restrict__ Wo2,
    const float* __restrict__ bo2, const float* __restrict__ gma,
    const float* __restrict__ bta, float* __restrict__ outp) {
  __shared__ float hL[8][128], xL[8][128], uL[8][128], rL[8][128];
  __shared__ float2 lnr[8][2];
  const int tid = threadIdx.x;
  const int col = tid & 127, g = tid >> 7;
  const int base = blockIdx.x * 8;
  const int node = base + g;

  hL[g][col] = hsrc[(size_t)node * 128 + col];
  float xv = 0.f;
  if (vmask[node]) {
    const int bb = node >> 8;
    const int nb = bstart[bb + 1] - bstart[bb];
    const int nq = (nb + 63) >> 6;
    float2 ms0 = msbuf[node * 4 + 0];
    float2 ms1 = nq > 1 ? msbuf[node * 4 + 1] : make_float2(-1e30f, 0.f);
    float2 ms2 = nq > 2 ? msbuf[node * 4 + 2] : make_float2(-1e30f, 0.f);
    float2 ms3 = nq > 3 ? msbuf[node * 4 + 3] : make_float2(-1e30f, 0.f);
    float m = fmaxf(fmaxf(ms0.x, ms1.x), fmaxf(ms2.x, ms3.x));
    float w0 = __expf(ms0.x - m), w1 = __expf(ms1.x - m);
    float w2 = __expf(ms2.x - m), w3 = __expf(ms3.x - m);
    float den = w0 * ms0.y + w1 * ms1.y + w2 * ms2.y + w3 * ms3.y;
    size_t ab = (size_t)node * 512 + col;
    float num = w0 * aggp[ab];
    if (nq > 1) num += w1 * aggp[ab + 128];
    if (nq > 2) num += w2 * aggp[ab + 256];
    if (nq > 3) num += w3 * aggp[ab + 384];
    xv = num / den;
  }
  xL[g][col] = xv;
  __syncthreads();

  float a = 0.f;
#pragma unroll 8
  for (int k = 0; k < 128; k += 4) {
    const float4 x4 = *(const float4*)&xL[g][k];
    a = fmaf(x4.x, Wm2[(k + 0) * 128 + col], a);
    a = fmaf(x4.y, Wm2[(k + 1) * 128 + col], a);
    a = fmaf(x4.z, Wm2[(k + 2) * 128 + col], a);
    a = fmaf(x4.w, Wm2[(k + 3) * 128 + col], a);
  }
  uL[g][col] = a + bm2[col];
  __syncthreads();

  a = 0.f;
#pragma unroll 8
  for (int k = 0; k < 128; k += 4) {
    const float4 h4 = *(const float4*)&hL[g][k];
    a = fmaf(h4.x, Wo1[(k + 0) * 128 + col], a);
    a = fmaf(h4.y, Wo1[(k + 1) * 128 + col], a);
    a = fmaf(h4.z, Wo1[(k + 2) * 128 + col], a);
    a = fmaf(h4.w, Wo1[(k + 3) * 128 + col], a);
  }
#pragma unroll 8
  for (int k = 0; k < 128; k += 4) {
    const float4 u4 = *(const float4*)&uL[g][k];
    a = fmaf(u4.x, Wo1[(128 + k + 0) * 128 + col], a);
    a = fmaf(u4.y, Wo1[(128 + k + 1) * 128 + col], a);
    a = fmaf(u4.z, Wo1[(128 + k + 2) * 128 + col], a);
    a = fmaf(u4.w, Wo1[(128 + k + 3) * 128 + col], a);
  }
  rL[g][col] = fmaxf(a + bo1[col], 0.f);
  __syncthreads();

  a = 0.f;
#pragma unroll 8
  for (int k = 0; k < 128; k += 4) {
    const float4 r4 = *(const float4*)&rL[g][k];
    a = fmaf(r4.x, Wo2[(k + 0) * 128 + col], a);
    a = fmaf(r4.y, Wo2[(k + 1) * 128 + col], a);
    a = fmaf(r4.z, Wo2[(k + 2) * 128 + col], a);
    a = fmaf(r4.w, Wo2[(k + 3) * 128 + col], a);
  }
  xL[g][col] = hL[g][col] + a + bo2[col];
  __syncthreads();

  const int w = tid >> 6, l = tid & 63;
  const int gg = w >> 1, hf = w & 1, cc = 64 * hf + l;
  float x = xL[gg][cc];
  float s = x, ss = x * x;
#pragma unroll
  for (int o = 1; o < 64; o <<= 1) {
    s += __shfl_xor(s, o);
    ss += __shfl_xor(ss, o);
  }
  if (l == 0) lnr[gg][hf] = make_float2(s, ss);
  __syncthreads();
  const float2 A = lnr[gg][0], Bv = lnr[gg][1];
  const float S = A.x + Bv.x, SS = A.y + Bv.y;
  const float mu = S * (1.f / 128.f);
  const float var = SS * (1.f / 128.f) - mu * mu;
  const float inv = rsqrtf(var + 1e-5f);
  const int nd = base + gg;
  const int valid = vmask[nd];
  float o0 = valid ? (x - mu) * inv * gma[cc] + bta[cc] : 0.f;
  outp[(size_t)nd * 128 + cc] = o0;
}

// ---------------------------------------------------------------------------
extern "C" void kernel_launch(void* const* d_in, const int* in_sizes, int n_in,
                              void* d_out, int out_size, void* d_ws, size_t ws_size,
                              hipStream_t stream) {
  const float* h_in = (const float*)d_in[0];
  const float* ef = (const float*)d_in[1];
  const int* vmask = (const int*)d_in[2];
  const float* We1 = (const float*)d_in[3];
  const float* be1 = (const float*)d_in[4];
  const float* We2 = (const float*)d_in[5];
  const float* be2 = (const float*)d_in[6];
  const float* Wa1 = (const float*)d_in[7];
  const float* ba1 = (const float*)d_in[8];
  const float* Wa2 = (const float*)d_in[9];
  const float* ba2 = (const float*)d_in[10];
  const float* Wm1 = (const float*)d_in[11];
  const float* bm1 = (const float*)d_in[12];
  const float* Wm2 = (const float*)d_in[13];
  const float* bm2 = (const float*)d_in[14];
  const float* Wo1 = (const float*)d_in[15];
  const float* bo1 = (const float*)d_in[16];
  const float* Wo2 = (const float*)d_in[17];
  const float* bo2 = (const float*)d_in[18];
  const float* gma = (const float*)d_in[19];
  const float* bta = (const float*)d_in[20];

  char* ws = (char*)d_ws;
  short* we1p = (short*)(ws + 0);                    // 8192 B
  short* weap = (short*)(ws + 8192);                 // 32768 B
  short* wemp = (short*)(ws + 40960);                // 32768 B
  float* bea = (float*)(ws + 73728);                 // 512 B
  float* bem = (float*)(ws + 74240);                 // 512 B
  int* compact = (int*)(ws + 74752);                 // 8192 B
  int* bstart = (int*)(ws + 82944);                  // 64 B (9 ints)
  int* cnt = (int*)(ws + 83072);                     // 64 B
  float* asrcb = (float*)(ws + 83136);               // 1 MiB
  float* hmb = (float*)(ws + 83136 + 1048576);       // 1 MiB
  unsigned short* adst_bf = (unsigned short*)(ws + 83136 + 2097152);  // 512 KiB
  float* aggp = (float*)(ws + 83136 + 2621440);      // 4 MiB
  float2* msbuf = (float2*)(ws + 83136 + 2621440 + 4194304);  // 64 KiB

  fusedPre<<<dim3(402), dim3(256), 0, stream>>>(
      h_in, vmask, We1, We2, be2, Wa1, ba1, Wm1, bm1, we1p, weap, wemp, bea,
      bem, compact, bstart, cnt, asrcb, adst_bf, hmb);
  kernC<<<dim3(8192), dim3(256), 0, stream>>>(ef, compact, bstart, cnt, we1p,
                                              weap, wemp, asrcb, adst_bf, hmb,
                                              Wa2, be1, ba2, bea, bem, aggp,
                                              msbuf);
  kernD<<<dim3(256), dim3(1024), 0, stream>>>(h_in, vmask, bstart, aggp, msbuf,
                                              Wm2, bm2, Wo1, bo1, Wo2, bo2,
                                              gma, bta, (float*)d_out);
}

// Round 11
// 66.324 us; speedup vs baseline: 1.6104x; 1.6104x over previous
//
#include <hip/hip_runtime.h>

// AGDN graph layer, fused. B=8, L=256, H=128, E=32.
//  - edge_h never materialized: Wea = We2@Wa_edge, Wem = We2@Wm_edge precomputed.
//  - Wm2 hoisted out of the pair loop (softmax weights sum to 1).
//  - j-compaction: only valid j's processed (order-preserving per-batch slices).
//  - permuted cols -> per-lane parameter/epilogue accesses contiguous vectors.
//  - R11: REVERT to R8 kernC (R10's wave-independent variant regressed 58.6->84
//    despite fewer barriers/conflicts — neither was binding). ONE change: DENSE
//    WORK LIST. fusedPre emits worklist[(v<<2)|q] for exactly the chunks with
//    work; kernC block bid executes worklist[bid]. R8 dispatched 8192 blocks of
//    which ~3/4 exited instantly (invalid node or empty chunk), leaving CUs
//    underfilled (Occ 22%). R4-vs-R6 evidence: denser block streams fill better.

typedef __attribute__((ext_vector_type(8))) short bhalf8;
typedef __attribute__((ext_vector_type(4))) float f32x4;

__device__ __forceinline__ short f2bf(float f) {
  union { float f; unsigned u; } v; v.f = f;
  unsigned r = (v.u + 0x7FFFu + ((v.u >> 16) & 1u)) >> 16;  // RNE
  return (short)r;
}
__device__ __forceinline__ unsigned cvt_pk(float lo, float hi) {
  unsigned r;
  asm("v_cvt_pk_bf16_f32 %0, %1, %2" : "=v"(r) : "v"(lo), "v"(hi));
  return r;
}
__device__ __forceinline__ float rawexp2(float x) {
  float r;
  asm("v_exp_f32 %0, %1" : "=v"(r) : "v"(x));
  return r;
}
__device__ __forceinline__ float rawrcp(float x) {
  float r;
  asm("v_rcp_f32 %0, %1" : "=v"(r) : "v"(x));
  return r;
}
__device__ __forceinline__ float bf2f(unsigned short x) {
  union { unsigned u; float f; } t; t.u = ((unsigned)x) << 16; return t.f;
}
__device__ __forceinline__ f32x4 mfma16(bhalf8 a, bhalf8 b, f32x4 c) {
  return __builtin_amdgcn_mfma_f32_16x16x32_bf16(a, b, c, 0, 0, 0);
}

// ---------------------------------------------------------------------------
// Fused pre-kernel: blocks 0..144 = weight packing; block 145 = compaction
// + per-batch bstart + DENSE WORK LIST; blocks 146..401 = node GEMVs.
// we1p cols permuted: frag (nt,l15) holds We1[:, 64*(nt>>2)+4*l15+(nt&3)].
// ---------------------------------------------------------------------------
__global__ __launch_bounds__(256) void fusedPre(
    const float* __restrict__ hsrc, const int* __restrict__ vmask,
    const float* __restrict__ We1, const float* __restrict__ We2,
    const float* __restrict__ be2, const float* __restrict__ Wa1,
    const float* __restrict__ ba1, const float* __restrict__ Wm1,
    const float* __restrict__ bm1,
    short* __restrict__ we1p, short* __restrict__ weap, short* __restrict__ wemp,
    float* __restrict__ bea, float* __restrict__ bem,
    int* __restrict__ compact, int* __restrict__ bstart, int* __restrict__ cnt,
    int* __restrict__ worklist, int* __restrict__ nwork,
    float* __restrict__ asrcb, unsigned short* __restrict__ adst_bf,
    float* __restrict__ hmb) {
  __shared__ float shf[8][128];
  __shared__ int wsum[4];
  __shared__ int shNv;
  const int blk = blockIdx.x;
  const int tid = threadIdx.x;

  if (blk < 145) {  // ---------------- weight packing ----------------
    int u = blk * 256 + tid;
    if (u < 4096) {                       // We1 packed, PERMUTED h_mid cols
      int e = u & 7, lane = (u >> 3) & 63, nt = u >> 9;
      int k = 8 * (lane >> 4) + e;
      int n = 64 * (nt >> 2) + 4 * (lane & 15) + (nt & 3);
      we1p[u] = f2bf(We1[k * 128 + n]);
    } else if (u < 20480) {               // Wea packed, permuted h_out cols
      int v = u - 4096;
      int e = v & 7, lane = (v >> 3) & 63, nt = (v >> 9) & 7, ks = v >> 12;
      int k = 32 * ks + 8 * (lane >> 4) + e;
      int co = 64 * (nt >> 2) + 4 * (lane & 15) + (nt & 3);
      float a0 = 0.f, a1 = 0.f, a2 = 0.f, a3 = 0.f;
      for (int c = 0; c < 128; c += 4) {
        const float4 w4 = *(const float4*)&We2[k * 128 + c];
        a0 = fmaf(w4.x, Wa1[(256 + c + 0) * 128 + co], a0);
        a1 = fmaf(w4.y, Wa1[(256 + c + 1) * 128 + co], a1);
        a2 = fmaf(w4.z, Wa1[(256 + c + 2) * 128 + co], a2);
        a3 = fmaf(w4.w, Wa1[(256 + c + 3) * 128 + co], a3);
      }
      weap[v] = f2bf((a0 + a1) + (a2 + a3));
    } else if (u < 36864) {               // Wem packed, permuted h_out cols
      int v = u - 20480;
      int e = v & 7, lane = (v >> 3) & 63, nt = (v >> 9) & 7, ks = v >> 12;
      int k = 32 * ks + 8 * (lane >> 4) + e;
      int co = 64 * (nt >> 2) + 4 * (lane & 15) + (nt & 3);
      float a0 = 0.f, a1 = 0.f, a2 = 0.f, a3 = 0.f;
      for (int c = 0; c < 128; c += 4) {
        const float4 w4 = *(const float4*)&We2[k * 128 + c];
        a0 = fmaf(w4.x, Wm1[(128 + c + 0) * 128 + co], a0);
        a1 = fmaf(w4.y, Wm1[(128 + c + 1) * 128 + co], a1);
        a2 = fmaf(w4.z, Wm1[(128 + c + 2) * 128 + co], a2);
        a3 = fmaf(w4.w, Wm1[(128 + c + 3) * 128 + co], a3);
      }
      wemp[v] = f2bf((a0 + a1) + (a2 + a3));
    } else if (u < 36992) {
      int hc = u - 36864;
      float acc = ba1[hc];
      for (int c = 0; c < 128; ++c)
        acc = fmaf(be2[c], Wa1[(256 + c) * 128 + hc], acc);
      bea[hc] = acc;
    } else if (u < 37120) {
      int hc = u - 36992;
      float acc = bm1[hc];
      for (int c = 0; c < 128; ++c)
        acc = fmaf(be2[c], Wm1[(128 + c) * 128 + hc], acc);
      bem[hc] = acc;
    }
  } else if (blk == 145) {  // ------- compaction + dense work list -------
    int loc[8], c = 0;
#pragma unroll
    for (int q = 0; q < 8; ++q) {
      int v = vmask[tid * 8 + q] != 0;
      loc[q] = v;
      c += v;
    }
    const int l = tid & 63, w = tid >> 6;
    int pre = c;
#pragma unroll
    for (int o = 1; o < 64; o <<= 1) {
      int t = __shfl_up(pre, o);
      if (l >= o) pre += t;
    }
    if (l == 63) wsum[w] = pre;
    __syncthreads();
    int base = 0;
    for (int q = 0; q < w; ++q) base += wsum[q];
    int off = base + pre - c;
    if ((tid & 31) == 0) bstart[tid >> 5] = off;
#pragma unroll
    for (int q = 0; q < 8; ++q)
      if (loc[q]) compact[off++] = tid * 8 + q;
    if (tid == 255) { cnt[0] = off; bstart[8] = off; shNv = off; }
    __syncthreads();   // compact/bstart/shNv complete

    // ---- dense work list: one entry (v<<2)|q per chunk with work ----
    const int nvv = shNv;
    int nqv[8], c2 = 0;
#pragma unroll
    for (int s = 0; s < 8; ++s) {
      int r = tid * 8 + s;
      int nq = 0;
      if (r < nvv) {
        int node = compact[r];
        int bb = node >> 8;
        int nbv = bstart[bb + 1] - bstart[bb];
        nq = (nbv + 63) >> 6;
        if (nq > 4) nq = 4;
      }
      nqv[s] = nq;
      c2 += nq;
    }
    int pre2 = c2;
#pragma unroll
    for (int o = 1; o < 64; o <<= 1) {
      int t = __shfl_up(pre2, o);
      if (l >= o) pre2 += t;
    }
    if (l == 63) wsum[w] = pre2;
    __syncthreads();
    int base2 = 0;
    for (int q = 0; q < w; ++q) base2 += wsum[q];
    int off2 = base2 + pre2 - c2;
#pragma unroll
    for (int s = 0; s < 8; ++s) {
      int r = tid * 8 + s;
      for (int q = 0; q < nqv[s]; ++q) worklist[off2++] = (r << 2) | q;
    }
    if (tid == 255) nwork[0] = off2;
  } else {  // ---------------- node GEMVs ----------------
    const int base = (blk - 146) * 8;
    const int col = tid & 127, half = tid >> 7;
#pragma unroll
    for (int g = 0; g < 4; ++g)
      shf[half * 4 + g][col] = hsrc[(size_t)(base + half * 4 + g) * 128 + col];
    __syncthreads();
    float aS[4], aD[4], aM[4];
#pragma unroll
    for (int g = 0; g < 4; ++g) { aS[g] = 0.f; aD[g] = 0.f; aM[g] = 0.f; }
    for (int k = 0; k < 128; k += 4) {
      float s0 = Wa1[(k + 0) * 128 + col], s1 = Wa1[(k + 1) * 128 + col];
      float s2 = Wa1[(k + 2) * 128 + col], s3 = Wa1[(k + 3) * 128 + col];
      float d0 = Wa1[(128 + k + 0) * 128 + col], d1 = Wa1[(128 + k + 1) * 128 + col];
      float d2 = Wa1[(128 + k + 2) * 128 + col], d3 = Wa1[(128 + k + 3) * 128 + col];
      float m0 = Wm1[(k + 0) * 128 + col], m1 = Wm1[(k + 1) * 128 + col];
      float m2 = Wm1[(k + 2) * 128 + col], m3 = Wm1[(k + 3) * 128 + col];
#pragma unroll
      for (int g = 0; g < 4; ++g) {
        const float4 hv = *(const float4*)&shf[half * 4 + g][k];
        aS[g] = fmaf(hv.x, s0, fmaf(hv.y, s1, fmaf(hv.z, s2, fmaf(hv.w, s3, aS[g]))));
        aD[g] = fmaf(hv.x, d0, fmaf(hv.y, d1, fmaf(hv.z, d2, fmaf(hv.w, d3, aD[g]))));
        aM[g] = fmaf(hv.x, m0, fmaf(hv.y, m1, fmaf(hv.z, m2, fmaf(hv.w, m3, aM[g]))));
      }
    }
#pragma unroll
    for (int g = 0; g < 4; ++g) {
      size_t o = (size_t)(base + half * 4 + g) * 128 + col;
      asrcb[o] = aS[g];
      adst_bf[o] = (unsigned short)f2bf(aD[g]);
      hmb[o] = aM[g];
    }
  }
}

// ---------------------------------------------------------------------------
// Kernel C (R8 structure): block bid executes worklist[bid] = (v<<2)|q.
// 4 waves: wave w -> jh=w>>1 (32-j half), hh=w&1 (64-h half); tile 32j x 64h.
// Outputs UNNORMALIZED agg + (m_loc, s_loc) per chunk for kernD merge.
// ---------------------------------------------------------------------------
__global__ __launch_bounds__(256) void kernC(
    const float* __restrict__ ef, const int* __restrict__ compact,
    const int* __restrict__ bstart, const int* __restrict__ worklist,
    const int* __restrict__ nwork,
    const short* __restrict__ we1p, const short* __restrict__ weap,
    const short* __restrict__ wemp, const float* __restrict__ asrcb,
    const unsigned short* __restrict__ adst_bf, const float* __restrict__ hmb,
    const float* __restrict__ wa2, const float* __restrict__ be1,
    const float* __restrict__ ba2, const float* __restrict__ bea,
    const float* __restrict__ bem, float* __restrict__ aggp,
    float2* __restrict__ msbuf) {
  if ((int)blockIdx.x >= nwork[0]) return;   // dense: only a contiguous tail exits
  const int wl = worklist[blockIdx.x];
  const int v = wl >> 2;
  const int q = wl & 3;
  const int blk = compact[v];
  const int b = blk >> 8;
  const int jb0 = bstart[b];
  const int nb = bstart[b + 1] - jb0;
  const int tid = threadIdx.x;

  __shared__ short Tl[64 * 128];                  // 16KB, XOR-swizzled rows
  __shared__ float att2[2][64];
  __shared__ float wtil[64];
  __shared__ __align__(16) float asr_s[128], hm_s[128], wa2_s[128];
  __shared__ __align__(16) float be1_s[128];
  __shared__ __align__(16) float agg2[2][128];

  const int w = tid >> 6, l = tid & 63;
  const int l15 = l & 15, l4 = l >> 4;
  const int jh = w >> 1, hh = w & 1;

  // valid-j row indices for this lane's T rows, then EF loads (early issue)
  float4 f0[2], f1[2];
#pragma unroll
  for (int m = 0; m < 2; ++m) {
    int idx = q * 64 + 32 * jh + 16 * m + l15;
    int jr = compact[jb0 + (idx < nb ? idx : nb - 1)] & 255;
    const float* p = ef + (((size_t)blk * 256 + jr) * 32 + 8 * l4);
    f0[m] = *(const float4*)p;
    f1[m] = *(const float4*)(p + 4);
  }

  if (tid < 128) {
    asr_s[tid] = asrcb[(size_t)blk * 128 + tid] + bea[tid];
    hm_s[tid] = hmb[(size_t)blk * 128 + tid] + bem[tid];
    wa2_s[tid] = wa2[tid];
    be1_s[tid] = be1[tid];
  }
  __syncthreads();

  const float ba2v = ba2[0];
  const float RS = 0.08838834764831845f;          // 1/sqrt(128)
  const f32x4 vz = {0.f, 0.f, 0.f, 0.f};
  const f32x4 asv = *(const f32x4*)&asr_s[hh * 64 + 4 * l15];
  const f32x4 wav = *(const f32x4*)&wa2_s[hh * 64 + 4 * l15];
  const f32x4 b4 = *(const f32x4*)&be1_s[hh * 64 + 4 * l15];  // permuted bias
  float whalf = wav[0] + wav[1] + wav[2] + wav[3];
  whalf += __shfl_xor(whalf, 1);
  whalf += __shfl_xor(whalf, 2);
  whalf += __shfl_xor(whalf, 4);
  whalf += __shfl_xor(whalf, 8);

  // ---- T = relu(EF @ We1perm + be1perm) -> Tl (natural h_mid order) ----
  {
    f32x4 acc[2][4];
#pragma unroll
    for (int m = 0; m < 2; ++m)
#pragma unroll
      for (int n = 0; n < 4; ++n) acc[m][n] = vz;
#pragma unroll
    for (int m = 0; m < 2; ++m) {
      union { bhalf8 v8; unsigned u[4]; } a;
      a.u[0] = cvt_pk(f0[m].x, f0[m].y);
      a.u[1] = cvt_pk(f0[m].z, f0[m].w);
      a.u[2] = cvt_pk(f1[m].x, f1[m].y);
      a.u[3] = cvt_pk(f1[m].z, f1[m].w);
#pragma unroll
      for (int n = 0; n < 4; ++n) {
        bhalf8 bfr = *(const bhalf8*)(we1p + (size_t)((hh * 4 + n) * 64 + l) * 8);
        acc[m][n] = mfma16(a.v8, bfr, acc[m][n]);
      }
    }
    // lane's 4 n-values = 4 consecutive h_mid (64hh+4*l15+n) at fixed j:
    // bias-add, relu, 2x cvt_pk, one ds_write_b64 per (m,r).
#pragma unroll
    for (int m = 0; m < 2; ++m)
#pragma unroll
      for (int r = 0; r < 4; ++r) {
        int jl = 32 * jh + 16 * m + 4 * l4 + r;
        float v0 = fmaxf(acc[m][0][r] + b4[0], 0.f);
        float v1 = fmaxf(acc[m][1][r] + b4[1], 0.f);
        float v2 = fmaxf(acc[m][2][r] + b4[2], 0.f);
        float v3 = fmaxf(acc[m][3][r] + b4[3], 0.f);
        uint2 pk;
        pk.x = cvt_pk(v0, v1);
        pk.y = cvt_pk(v2, v3);
        int byte = (jl * 256 + 128 * hh + 8 * l15) ^ ((jl & 7) << 4);
        *(uint2*)((char*)Tl + byte) = pk;
      }
  }
  __syncthreads();

  // ---- attention logits: EA = T @ Wea ----
  {
    ushort4 adp[2][4];
#pragma unroll
    for (int m = 0; m < 2; ++m)
#pragma unroll
      for (int r = 0; r < 4; ++r) {
        int idx = q * 64 + 32 * jh + 16 * m + 4 * l4 + r;
        int jg = compact[jb0 + (idx < nb ? idx : nb - 1)] & 255;
        adp[m][r] = *(const ushort4*)(adst_bf + (size_t)(b * 256 + jg) * 128 +
                                      hh * 64 + 4 * l15);
      }
    f32x4 acc[2][4];
#pragma unroll
    for (int m = 0; m < 2; ++m)
#pragma unroll
      for (int n = 0; n < 4; ++n) acc[m][n] = vz;
#pragma unroll
    for (int ks = 0; ks < 4; ++ks) {
      bhalf8 af[2];
#pragma unroll
      for (int m = 0; m < 2; ++m) {
        int jl = 32 * jh + 16 * m + l15;
        int byte = (jl * 256 + ks * 64 + 16 * l4) ^ ((jl & 7) << 4);
        af[m] = *(const bhalf8*)((const char*)Tl + byte);
      }
#pragma unroll
      for (int n = 0; n < 4; ++n) {
        bhalf8 bf2 = *(const bhalf8*)(weap + (size_t)((ks * 8 + hh * 4 + n) * 64 + l) * 8);
#pragma unroll
        for (int m = 0; m < 2; ++m) acc[m][n] = mfma16(af[m], bf2, acc[m][n]);
      }
    }
    // sum_h wa2*tanh(x) = whalf - 2*sum_h wa2*rcp(exp2(2log2e*x)+1)
#pragma unroll
    for (int m = 0; m < 2; ++m)
#pragma unroll
      for (int r = 0; r < 4; ++r) {
        float racc = 0.f;
        float adv[4] = {bf2f(adp[m][r].x), bf2f(adp[m][r].y),
                        bf2f(adp[m][r].z), bf2f(adp[m][r].w)};
#pragma unroll
        for (int n = 0; n < 4; ++n) {
          float x = acc[m][n][r] + asv[n] + adv[n];
          float e = rawexp2(x * 2.885390082f);
          racc = fmaf(wav[n], rawrcp(e + 1.f), racc);
        }
        racc += __shfl_xor(racc, 1);
        racc += __shfl_xor(racc, 2);
        racc += __shfl_xor(racc, 4);
        racc += __shfl_xor(racc, 8);
        if (l15 == 0)
          att2[hh][32 * jh + 16 * m + 4 * l4 + r] = whalf - 2.f * racc;
      }
  }
  __syncthreads();

  // ---- partial softmax over this chunk's 64 slots (wave 0) ----
  if (w == 0) {
    int idx = q * 64 + l;
    float s = (idx < nb) ? (att2[0][l] + att2[1][l] + ba2v) * RS : -1e30f;
    float mx = s;
#pragma unroll
    for (int o = 1; o < 64; o <<= 1) mx = fmaxf(mx, __shfl_xor(mx, o));
    float e = __expf(s - mx);
    wtil[l] = e;
    float sm = e;
#pragma unroll
    for (int o = 1; o < 64; o <<= 1) sm += __shfl_xor(sm, o);
    if (l == 0) msbuf[blk * 4 + q] = make_float2(mx, sm);
  }
  __syncthreads();

  // ---- message: EM = T @ Wem ; weighted relu-agg (unnormalized) ----
  {
    const f32x4 hv = *(const f32x4*)&hm_s[hh * 64 + 4 * l15];
    f32x4 acc[2][4];
#pragma unroll
    for (int m = 0; m < 2; ++m)
#pragma unroll
      for (int n = 0; n < 4; ++n) acc[m][n] = vz;
#pragma unroll
    for (int ks = 0; ks < 4; ++ks) {
      bhalf8 af[2];
#pragma unroll
      for (int m = 0; m < 2; ++m) {
        int jl = 32 * jh + 16 * m + l15;
        int byte = (jl * 256 + ks * 64 + 16 * l4) ^ ((jl & 7) << 4);
        af[m] = *(const bhalf8*)((const char*)Tl + byte);
      }
#pragma unroll
      for (int n = 0; n < 4; ++n) {
        bhalf8 bf2 = *(const bhalf8*)(wemp + (size_t)((ks * 8 + hh * 4 + n) * 64 + l) * 8);
#pragma unroll
        for (int m = 0; m < 2; ++m) acc[m][n] = mfma16(af[m], bf2, acc[m][n]);
      }
    }
    float part[4] = {0.f, 0.f, 0.f, 0.f};
#pragma unroll
    for (int m = 0; m < 2; ++m)
#pragma unroll
      for (int r = 0; r < 4; ++r) {
        int jl = 32 * jh + 16 * m + 4 * l4 + r;
        float wj = wtil[jl];
#pragma unroll
        for (int n = 0; n < 4; ++n) {
          float vv = fmaxf(acc[m][n][r] + hv[n], 0.f);
          part[n] = fmaf(wj, vv, part[n]);
        }
      }
#pragma unroll
    for (int n = 0; n < 4; ++n) {
      part[n] += __shfl_xor(part[n], 16);
      part[n] += __shfl_xor(part[n], 32);
    }
    if (l4 == 0) {
      f32x4 pv = {part[0], part[1], part[2], part[3]};
      *(f32x4*)&agg2[jh][hh * 64 + 4 * l15] = pv;
    }
  }
  __syncthreads();
  if (tid < 128)
    aggp[((size_t)blk * 4 + q) * 128 + tid] = agg2[0][tid] + agg2[1][tid];
}

// ---------------------------------------------------------------------------
// Kernel D (unchanged from R8): merge nq chunks; MLP; residual; LN; mask.
// ---------------------------------------------------------------------------
__global__ __launch_bounds__(1024) void kernD(
    const float* __restrict__ hsrc, const int* __restrict__ vmask,
    const int* __restrict__ bstart, const float* __restrict__ aggp,
    const float2* __restrict__ msbuf, const float* __restrict__ Wm2,
    const float* __restrict__ bm2, const float* __restrict__ Wo1,
    const float* __restrict__ bo1, const float* __restrict__ Wo2,
    const float* __restrict__ bo2, const float* __restrict__ gma,
    const float* __restrict__ bta, float* __restrict__ outp) {
  __shared__ float hL[8][128], xL[8][128], uL[8][128], rL[8][128];
  __shared__ float2 lnr[8][2];
  const int tid = threadIdx.x;
  const int col = tid & 127, g = tid >> 7;
  const int base = blockIdx.x * 8;
  const int node = base + g;

  hL[g][col] = hsrc[(size_t)node * 128 + col];
  float xv = 0.f;
  if (vmask[node]) {
    const int bb = node >> 8;
    const int nb = bstart[bb + 1] - bstart[bb];
    const int nq = (nb + 63) >> 6;
    float2 ms0 = msbuf[node * 4 + 0];
    float2 ms1 = nq > 1 ? msbuf[node * 4 + 1] : make_float2(-1e30f, 0.f);
    float2 ms2 = nq > 2 ? msbuf[node * 4 + 2] : make_float2(-1e30f, 0.f);
    float2 ms3 = nq > 3 ? msbuf[node * 4 + 3] : make_float2(-1e30f, 0.f);
    float m = fmaxf(fmaxf(ms0.x, ms1.x), fmaxf(ms2.x, ms3.x));
    float w0 = __expf(ms0.x - m), w1 = __expf(ms1.x - m);
    float w2 = __expf(ms2.x - m), w3 = __expf(ms3.x - m);
    float den = w0 * ms0.y + w1 * ms1.y + w2 * ms2.y + w3 * ms3.y;
    size_t ab = (size_t)node * 512 + col;
    float num = w0 * aggp[ab];
    if (nq > 1) num += w1 * aggp[ab + 128];
    if (nq > 2) num += w2 * aggp[ab + 256];
    if (nq > 3) num += w3 * aggp[ab + 384];
    xv = num / den;
  }
  xL[g][col] = xv;
  __syncthreads();

  float a = 0.f;
#pragma unroll 8
  for (int k = 0; k < 128; k += 4) {
    const float4 x4 = *(const float4*)&xL[g][k];
    a = fmaf(x4.x, Wm2[(k + 0) * 128 + col], a);
    a = fmaf(x4.y, Wm2[(k + 1) * 128 + col], a);
    a = fmaf(x4.z, Wm2[(k + 2) * 128 + col], a);
    a = fmaf(x4.w, Wm2[(k + 3) * 128 + col], a);
  }
  uL[g][col] = a + bm2[col];
  __syncthreads();

  a = 0.f;
#pragma unroll 8
  for (int k = 0; k < 128; k += 4) {
    const float4 h4 = *(const float4*)&hL[g][k];
    a = fmaf(h4.x, Wo1[(k + 0) * 128 + col], a);
    a = fmaf(h4.y, Wo1[(k + 1) * 128 + col], a);
    a = fmaf(h4.z, Wo1[(k + 2) * 128 + col], a);
    a = fmaf(h4.w, Wo1[(k + 3) * 128 + col], a);
  }
#pragma unroll 8
  for (int k = 0; k < 128; k += 4) {
    const float4 u4 = *(const float4*)&uL[g][k];
    a = fmaf(u4.x, Wo1[(128 + k + 0) * 128 + col], a);
    a = fmaf(u4.y, Wo1[(128 + k + 1) * 128 + col], a);
    a = fmaf(u4.z, Wo1[(128 + k + 2) * 128 + col], a);
    a = fmaf(u4.w, Wo1[(128 + k + 3) * 128 + col], a);
  }
  rL[g][col] = fmaxf(a + bo1[col], 0.f);
  __syncthreads();

  a = 0.f;
#pragma unroll 8
  for (int k = 0; k < 128; k += 4) {
    const float4 r4 = *(const float4*)&rL[g][k];
    a = fmaf(r4.x, Wo2[(k + 0) * 128 + col], a);
    a = fmaf(r4.y, Wo2[(k + 1) * 128 + col], a);
    a = fmaf(r4.z, Wo2[(k + 2) * 128 + col], a);
    a = fmaf(r4.w, Wo2[(k + 3) * 128 + col], a);
  }
  xL[g][col] = hL[g][col] + a + bo2[col];
  __syncthreads();

  const int w = tid >> 6, l = tid & 63;
  const int gg = w >> 1, hf = w & 1, cc = 64 * hf + l;
  float x = xL[gg][cc];
  float s = x, ss = x * x;
#pragma unroll
  for (int o = 1; o < 64; o <<= 1) {
    s += __shfl_xor(s, o);
    ss += __shfl_xor(ss, o);
  }
  if (l == 0) lnr[gg][hf] = make_float2(s, ss);
  __syncthreads();
  const float2 A = lnr[gg][0], Bv = lnr[gg][1];
  const float S = A.x + Bv.x, SS = A.y + Bv.y;
  const float mu = S * (1.f / 128.f);
  const float var = SS * (1.f / 128.f) - mu * mu;
  const float inv = rsqrtf(var + 1e-5f);
  const int nd = base + gg;
  const int valid = vmask[nd];
  float o0 = valid ? (x - mu) * inv * gma[cc] + bta[cc] : 0.f;
  outp[(size_t)nd * 128 + cc] = o0;
}

// ---------------------------------------------------------------------------
extern "C" void kernel_launch(void* const* d_in, const int* in_sizes, int n_in,
                              void* d_out, int out_size, void* d_ws, size_t ws_size,
                              hipStream_t stream) {
  const float* h_in = (const float*)d_in[0];
  const float* ef = (const float*)d_in[1];
  const int* vmask = (const int*)d_in[2];
  const float* We1 = (const float*)d_in[3];
  const float* be1 = (const float*)d_in[4];
  const float* We2 = (const float*)d_in[5];
  const float* be2 = (const float*)d_in[6];
  const float* Wa1 = (const float*)d_in[7];
  const float* ba1 = (const float*)d_in[8];
  const float* Wa2 = (const float*)d_in[9];
  const float* ba2 = (const float*)d_in[10];
  const float* Wm1 = (const float*)d_in[11];
  const float* bm1 = (const float*)d_in[12];
  const float* Wm2 = (const float*)d_in[13];
  const float* bm2 = (const float*)d_in[14];
  const float* Wo1 = (const float*)d_in[15];
  const float* bo1 = (const float*)d_in[16];
  const float* Wo2 = (const float*)d_in[17];
  const float* bo2 = (const float*)d_in[18];
  const float* gma = (const float*)d_in[19];
  const float* bta = (const float*)d_in[20];

  char* ws = (char*)d_ws;
  short* we1p = (short*)(ws + 0);                    // 8192 B
  short* weap = (short*)(ws + 8192);                 // 32768 B
  short* wemp = (short*)(ws + 40960);                // 32768 B
  float* bea = (float*)(ws + 73728);                 // 512 B
  float* bem = (float*)(ws + 74240);                 // 512 B
  int* compact = (int*)(ws + 74752);                 // 8192 B
  int* bstart = (int*)(ws + 82944);                  // 64 B (9 ints)
  int* cnt = (int*)(ws + 83072);                     // 64 B
  int* worklist = (int*)(ws + 83136);                // 32768 B
  int* nwork = (int*)(ws + 115904);                  // 64 B
  float* asrcb = (float*)(ws + 115968);              // 1 MiB
  float* hmb = (float*)(ws + 115968 + 1048576);      // 1 MiB
  unsigned short* adst_bf = (unsigned short*)(ws + 115968 + 2097152);  // 512 KiB
  float* aggp = (float*)(ws + 115968 + 2621440);     // 4 MiB
  float2* msbuf = (float2*)(ws + 115968 + 2621440 + 4194304);  // 64 KiB

  fusedPre<<<dim3(402), dim3(256), 0, stream>>>(
      h_in, vmask, We1, We2, be2, Wa1, ba1, Wm1, bm1, we1p, weap, wemp, bea,
      bem, compact, bstart, cnt, worklist, nwork, asrcb, adst_bf, hmb);
  kernC<<<dim3(8192), dim3(256), 0, stream>>>(ef, compact, bstart, worklist,
                                              nwork, we1p, weap, wemp, asrcb,
                                              adst_bf, hmb, Wa2, be1, ba2, bea,
                                              bem, aggp, msbuf);
  kernD<<<dim3(256), dim3(1024), 0, stream>>>(h_in, vmask, bstart, aggp, msbuf,
                                              Wm2, bm2, Wo1, bo1, Wo2, bo2,
                                              gma, bta, (float*)d_out);
}